// Round 7
// baseline (35.569 us; speedup 1.0000x reference)
//
#include <hip/hip_runtime.h>

#define B_SZ 32
#define T_PH 512
#define H_DIM 256
#define N_EDGES 255
#define MAX_LEN 4096

typedef float f32x4 __attribute__((ext_vector_type(4)));

// ---------------- Kernel A: scan + bin bisects + coalesced packed-frame fill ----------
// (round-3 version + one extra int store of mel)
__global__ void prep_kernel(const int* __restrict__ dur,
                            const float* __restrict__ pt,
                            const float* __restrict__ et,
                            const float* __restrict__ pbins,
                            const float* __restrict__ ebins,
                            int* __restrict__ frames,
                            int* __restrict__ mel_i32,
                            float* __restrict__ mel_out) {
    const int b = blockIdx.x;
    const int tid = threadIdx.x;
    __shared__ int cs[T_PH];
    __shared__ int packv[T_PH];
    __shared__ float pb[N_EDGES];
    __shared__ float eb[N_EDGES];

    if (tid < N_EDGES) pb[tid] = pbins[tid];
    else if (tid >= 256 && tid < 256 + N_EDGES) eb[tid - 256] = ebins[tid - 256];

    const int d = dur[b * T_PH + tid];
    cs[tid] = d;
    __syncthreads();
#pragma unroll
    for (int off = 1; off < T_PH; off <<= 1) {
        int v = (tid >= off) ? cs[tid - off] : 0;
        __syncthreads();
        cs[tid] += v;
        __syncthreads();
    }

    const float pv = pt[b * T_PH + tid];
    const float ev = et[b * T_PH + tid];
    int lo = 0, hi = N_EDGES;
    while (lo < hi) { int m = (lo + hi) >> 1; if (pb[m] < pv) lo = m + 1; else hi = m; }
    const int pi = lo;
    lo = 0; hi = N_EDGES;
    while (lo < hi) { int m = (lo + hi) >> 1; if (eb[m] < ev) lo = m + 1; else hi = m; }
    const int ei = lo;
    packv[tid] = tid | (pi << 9) | (ei << 17);
    __syncthreads();

    const int mel = cs[T_PH - 1];

    const int t0 = tid * 8;
    int p = 0;
    if (t0 < mel) {
        int l = 0, h = T_PH;
        while (l < h) { int m = (l + h) >> 1; if (cs[m] > t0) h = m; else l = m + 1; }
        p = l;
    }
    int o[8];
#pragma unroll
    for (int j = 0; j < 8; ++j) {
        const int t = t0 + j;
        int v = -1;
        if (t < mel) {
            while (cs[p] <= t) ++p;
            v = packv[p];
        }
        o[j] = v;
    }
    int4* fr = (int4*)(frames + (size_t)b * MAX_LEN);
    fr[tid * 2]     = make_int4(o[0], o[1], o[2], o[3]);
    fr[tid * 2 + 1] = make_int4(o[4], o[5], o[6], o[7]);

    if (tid == T_PH - 1) {
        mel_i32[b] = mel;
        mel_out[b] = (float)mel;  // exact for < 2^24
    }
}

// ---------------- Kernel B: R3 structure + scalar-mel tail fast path ----------------
// 4 frames/block, 1 frame/wave, 32768 blocks. Tail blocks: zero NT stores with
// no vector-load dependency (fillBuffer-like). Valid/boundary: R3 gather path.
__global__ void expand_kernel(const float* __restrict__ x,
                              const float* __restrict__ pemb,
                              const float* __restrict__ eemb,
                              const int* __restrict__ frames,
                              const int* __restrict__ mel_i32,
                              float* __restrict__ out) {
    const int sub   = threadIdx.x >> 6;
    const int lane4 = threadIdx.x & 63;
    const int fbase = blockIdx.x * 4;
    const int b     = fbase >> 12;
    const int t     = (fbase & (MAX_LEN - 1));   // frame-in-row of block start
    const int mel   = mel_i32[b];                // hot scalar (32 ints total)

    const int frame = fbase + sub;
    f32x4* op = (f32x4*)out + (size_t)frame * 64 + lane4;
    const f32x4 z = {0.f, 0.f, 0.f, 0.f};

    if (t >= mel) {                 // whole block past mel: pure zero stream
        __builtin_nontemporal_store(z, op);
        return;
    }

    if (t + sub < mel) {            // valid frame (wave-uniform)
        const int pk = frames[frame];
        const int ph = pk & 511;
        const int pi = (pk >> 9) & 255;
        const int ei = (pk >> 17) & 255;
        const f32x4 a = ((const f32x4*)(x    + (size_t)(b * T_PH + ph) * H_DIM))[lane4];
        const f32x4 p = ((const f32x4*)(pemb + (size_t)pi * H_DIM))[lane4];
        const f32x4 e = ((const f32x4*)(eemb + (size_t)ei * H_DIM))[lane4];
        __builtin_nontemporal_store(a + p + e, op);
    } else {                        // boundary block's tail frames
        __builtin_nontemporal_store(z, op);
    }
}

extern "C" void kernel_launch(void* const* d_in, const int* in_sizes, int n_in,
                              void* d_out, int out_size, void* d_ws, size_t ws_size,
                              hipStream_t stream) {
    const float* x     = (const float*)d_in[0];
    const float* pt    = (const float*)d_in[1];
    const float* et    = (const float*)d_in[2];
    const float* pbins = (const float*)d_in[3];
    const float* ebins = (const float*)d_in[4];
    const float* pemb  = (const float*)d_in[5];
    const float* eemb  = (const float*)d_in[6];
    const int*   dur   = (const int*)d_in[7];

    float* out = (float*)d_out;                            // 32*4096*256 f32
    float* mel_out = out + (size_t)B_SZ * MAX_LEN * H_DIM; // 32 f32 (tuple tail)

    int* frames  = (int*)d_ws;                             // 512 KB packed indices
    int* mel_i32 = frames + B_SZ * MAX_LEN;                // 128 B

    prep_kernel<<<B_SZ, T_PH, 0, stream>>>(dur, pt, et, pbins, ebins,
                                           frames, mel_i32, mel_out);

    const int nframes = B_SZ * MAX_LEN;                    // 131072
    expand_kernel<<<nframes / 4, 256, 0, stream>>>(x, pemb, eemb,
                                                   frames, mel_i32, out);
}

// Round 8
// 32.451 us; speedup vs baseline: 1.0961x; 1.0961x over previous
//
#include <hip/hip_runtime.h>

#define B_SZ 32
#define T_PH 512
#define H_DIM 256
#define N_EDGES 255
#define MAX_LEN 4096

typedef float f32x4 __attribute__((ext_vector_type(4)));

// ---------------- Kernel A: shfl-scan (2 barriers) + bin bisects + packed fill -------
// One block (512 thr) per batch row. frames[b][t] = ph | pi<<9 | ei<<17 (or -1)
__global__ void prep_kernel(const int* __restrict__ dur,
                            const float* __restrict__ pt,
                            const float* __restrict__ et,
                            const float* __restrict__ pbins,
                            const float* __restrict__ ebins,
                            int* __restrict__ frames,
                            float* __restrict__ mel_out) {
    const int b = blockIdx.x;
    const int tid = threadIdx.x;
    const int wave = tid >> 6;
    const int lane = tid & 63;
    __shared__ int cs[T_PH];
    __shared__ int packv[T_PH];
    __shared__ int wsum[8];
    __shared__ float pb[N_EDGES];
    __shared__ float eb[N_EDGES];

    if (tid < N_EDGES) pb[tid] = pbins[tid];
    else if (tid >= 256 && tid < 256 + N_EDGES) eb[tid - 256] = ebins[tid - 256];

    const int d = dur[b * T_PH + tid];
    // wave-level inclusive scan (no barriers)
    int v = d;
#pragma unroll
    for (int off = 1; off < 64; off <<= 1) {
        int u = __shfl_up(v, off, 64);
        if (lane >= off) v += u;
    }
    if (lane == 63) wsum[wave] = v;
    __syncthreads();
    int woff = 0;
#pragma unroll
    for (int w = 0; w < 8; ++w) woff += (w < wave) ? wsum[w] : 0;
    v += woff;
    cs[tid] = v;

    // per-phoneme bin bisects (side='left'), bins in LDS
    const float pv = pt[b * T_PH + tid];
    const float ev = et[b * T_PH + tid];
    int lo = 0, hi = N_EDGES;
    while (lo < hi) { int m = (lo + hi) >> 1; if (pb[m] < pv) lo = m + 1; else hi = m; }
    const int pi = lo;
    lo = 0; hi = N_EDGES;
    while (lo < hi) { int m = (lo + hi) >> 1; if (eb[m] < ev) lo = m + 1; else hi = m; }
    const int ei = lo;
    packv[tid] = tid | (pi << 9) | (ei << 17);
    __syncthreads();

    const int mel = cs[T_PH - 1];

    // each thread resolves 8 consecutive frames: one LDS bisect + monotone walk
    const int t0 = tid * 8;
    int p = 0;
    if (t0 < mel) {
        int l = 0, h = T_PH;   // searchsorted(cs, t0, side='right')
        while (l < h) { int m = (l + h) >> 1; if (cs[m] > t0) h = m; else l = m + 1; }
        p = l;
    }
    int o[8];
#pragma unroll
    for (int j = 0; j < 8; ++j) {
        const int t = t0 + j;
        int vv = -1;
        if (t < mel) {
            while (cs[p] <= t) ++p;
            vv = packv[p];
        }
        o[j] = vv;
    }
    int4* fr = (int4*)(frames + (size_t)b * MAX_LEN);
    fr[tid * 2]     = make_int4(o[0], o[1], o[2], o[3]);
    fr[tid * 2 + 1] = make_int4(o[4], o[5], o[6], o[7]);

    if (tid == T_PH - 1) mel_out[b] = (float)mel;  // exact for < 2^24
}

// ---------------- Kernel B: byte-identical to round-3 best (33.2 us) ----------------
__global__ void expand_kernel(const float* __restrict__ x,
                              const float* __restrict__ pemb,
                              const float* __restrict__ eemb,
                              const int* __restrict__ frames,
                              float* __restrict__ out) {
    const int sub   = threadIdx.x >> 6;
    const int lane4 = threadIdx.x & 63;
    const int frame = blockIdx.x * 4 + sub;
    const int b = frame >> 12;

    const int pk = frames[frame];            // wave-uniform broadcast
    f32x4 val = {0.f, 0.f, 0.f, 0.f};
    if (pk >= 0) {
        const int ph = pk & 511;
        const int pi = (pk >> 9) & 255;
        const int ei = (pk >> 17) & 255;
        const f32x4* xr = (const f32x4*)(x + (size_t)(b * T_PH + ph) * H_DIM);
        const f32x4* pr = (const f32x4*)(pemb + (size_t)pi * H_DIM);
        const f32x4* er = (const f32x4*)(eemb + (size_t)ei * H_DIM);
        const f32x4 a = xr[lane4];
        const f32x4 p = pr[lane4];
        const f32x4 e = er[lane4];
        val = a + p + e;
    }
    __builtin_nontemporal_store(val, (f32x4*)out + (size_t)frame * 64 + lane4);
}

extern "C" void kernel_launch(void* const* d_in, const int* in_sizes, int n_in,
                              void* d_out, int out_size, void* d_ws, size_t ws_size,
                              hipStream_t stream) {
    const float* x     = (const float*)d_in[0];
    const float* pt    = (const float*)d_in[1];
    const float* et    = (const float*)d_in[2];
    const float* pbins = (const float*)d_in[3];
    const float* ebins = (const float*)d_in[4];
    const float* pemb  = (const float*)d_in[5];
    const float* eemb  = (const float*)d_in[6];
    const int*   dur   = (const int*)d_in[7];

    float* out = (float*)d_out;                            // 32*4096*256 f32
    float* mel_out = out + (size_t)B_SZ * MAX_LEN * H_DIM; // 32 f32 (tuple tail)

    int* frames = (int*)d_ws;                              // 512 KB packed indices

    prep_kernel<<<B_SZ, T_PH, 0, stream>>>(dur, pt, et, pbins, ebins,
                                           frames, mel_out);

    const int nframes = B_SZ * MAX_LEN;                    // 131072
    expand_kernel<<<nframes / 4, 256, 0, stream>>>(x, pemb, eemb, frames, out);
}

// Round 9
// 32.134 us; speedup vs baseline: 1.1069x; 1.0099x over previous
//
#include <hip/hip_runtime.h>

#define B_SZ 32
#define T_PH 512
#define H_DIM 256
#define N_EDGES 255
#define MAX_LEN 4096

typedef float f32x4 __attribute__((ext_vector_type(4)));

// ---------------- Kernel A: shfl-scan (2 barriers) + bin bisects + packed fill -------
// (byte-identical to round-8)
__global__ void prep_kernel(const int* __restrict__ dur,
                            const float* __restrict__ pt,
                            const float* __restrict__ et,
                            const float* __restrict__ pbins,
                            const float* __restrict__ ebins,
                            int* __restrict__ frames,
                            float* __restrict__ mel_out) {
    const int b = blockIdx.x;
    const int tid = threadIdx.x;
    const int wave = tid >> 6;
    const int lane = tid & 63;
    __shared__ int cs[T_PH];
    __shared__ int packv[T_PH];
    __shared__ int wsum[8];
    __shared__ float pb[N_EDGES];
    __shared__ float eb[N_EDGES];

    if (tid < N_EDGES) pb[tid] = pbins[tid];
    else if (tid >= 256 && tid < 256 + N_EDGES) eb[tid - 256] = ebins[tid - 256];

    const int d = dur[b * T_PH + tid];
    int v = d;
#pragma unroll
    for (int off = 1; off < 64; off <<= 1) {
        int u = __shfl_up(v, off, 64);
        if (lane >= off) v += u;
    }
    if (lane == 63) wsum[wave] = v;
    __syncthreads();
    int woff = 0;
#pragma unroll
    for (int w = 0; w < 8; ++w) woff += (w < wave) ? wsum[w] : 0;
    v += woff;
    cs[tid] = v;

    const float pv = pt[b * T_PH + tid];
    const float ev = et[b * T_PH + tid];
    int lo = 0, hi = N_EDGES;
    while (lo < hi) { int m = (lo + hi) >> 1; if (pb[m] < pv) lo = m + 1; else hi = m; }
    const int pi = lo;
    lo = 0; hi = N_EDGES;
    while (lo < hi) { int m = (lo + hi) >> 1; if (eb[m] < ev) lo = m + 1; else hi = m; }
    const int ei = lo;
    packv[tid] = tid | (pi << 9) | (ei << 17);
    __syncthreads();

    const int mel = cs[T_PH - 1];

    const int t0 = tid * 8;
    int p = 0;
    if (t0 < mel) {
        int l = 0, h = T_PH;
        while (l < h) { int m = (l + h) >> 1; if (cs[m] > t0) h = m; else l = m + 1; }
        p = l;
    }
    int o[8];
#pragma unroll
    for (int j = 0; j < 8; ++j) {
        const int t = t0 + j;
        int vv = -1;
        if (t < mel) {
            while (cs[p] <= t) ++p;
            vv = packv[p];
        }
        o[j] = vv;
    }
    int4* fr = (int4*)(frames + (size_t)b * MAX_LEN);
    fr[tid * 2]     = make_int4(o[0], o[1], o[2], o[3]);
    fr[tid * 2 + 1] = make_int4(o[4], o[5], o[6], o[7]);

    if (tid == T_PH - 1) mel_out[b] = (float)mel;  // exact for < 2^24
}

// ---------------- Kernel B: R3/R8 structure + bijective XCD chunk swizzle ------------
// 32768 blocks, 4 frames/block, 1 frame/wave. XCD k owns frames [k*16384,(k+1)*16384)
// = 4 batch rows -> x span (2MB) + emb tables (0.5MB) L2-resident per XCD.
__global__ void expand_kernel(const float* __restrict__ x,
                              const float* __restrict__ pemb,
                              const float* __restrict__ eemb,
                              const int* __restrict__ frames,
                              float* __restrict__ out) {
    const int sub   = threadIdx.x >> 6;
    const int lane4 = threadIdx.x & 63;
    // bijective swizzle: physical bid -> virtual block; 32768 % 8 == 0
    const int bid = blockIdx.x;
    const int vb  = (bid & 7) * 4096 + (bid >> 3);
    const int frame = vb * 4 + sub;
    const int b = frame >> 12;

    const int pk = frames[frame];            // wave-uniform broadcast
    f32x4 val = {0.f, 0.f, 0.f, 0.f};
    if (pk >= 0) {
        const int ph = pk & 511;
        const int pi = (pk >> 9) & 255;
        const int ei = (pk >> 17) & 255;
        const f32x4* xr = (const f32x4*)(x + (size_t)(b * T_PH + ph) * H_DIM);
        const f32x4* pr = (const f32x4*)(pemb + (size_t)pi * H_DIM);
        const f32x4* er = (const f32x4*)(eemb + (size_t)ei * H_DIM);
        const f32x4 a = xr[lane4];
        const f32x4 p = pr[lane4];
        const f32x4 e = er[lane4];
        val = a + p + e;
    }
    __builtin_nontemporal_store(val, (f32x4*)out + (size_t)frame * 64 + lane4);
}

extern "C" void kernel_launch(void* const* d_in, const int* in_sizes, int n_in,
                              void* d_out, int out_size, void* d_ws, size_t ws_size,
                              hipStream_t stream) {
    const float* x     = (const float*)d_in[0];
    const float* pt    = (const float*)d_in[1];
    const float* et    = (const float*)d_in[2];
    const float* pbins = (const float*)d_in[3];
    const float* ebins = (const float*)d_in[4];
    const float* pemb  = (const float*)d_in[5];
    const float* eemb  = (const float*)d_in[6];
    const int*   dur   = (const int*)d_in[7];

    float* out = (float*)d_out;                            // 32*4096*256 f32
    float* mel_out = out + (size_t)B_SZ * MAX_LEN * H_DIM; // 32 f32 (tuple tail)

    int* frames = (int*)d_ws;                              // 512 KB packed indices

    prep_kernel<<<B_SZ, T_PH, 0, stream>>>(dur, pt, et, pbins, ebins,
                                           frames, mel_out);

    const int nframes = B_SZ * MAX_LEN;                    // 131072
    expand_kernel<<<nframes / 4, 256, 0, stream>>>(x, pemb, eemb, frames, out);
}